// Round 1
// 492.810 us; speedup vs baseline: 2.0967x; 2.0967x over previous
//
#include <hip/hip_runtime.h>

// Problem constants
#define B_  8
#define S_  512
#define H_  1024
#define NH_ 16
#define D_  64
#define M_  4096                       // B_*S_
#define HH_ ((size_t)H_ * H_)          // 1,048,576  (one weight matrix)
#define MH_ ((size_t)M_ * H_)          // 4,194,304  (one [B,S,H] tensor)

typedef __attribute__((ext_vector_type(8))) short short8;
typedef __attribute__((ext_vector_type(4))) float f32x4;

// ---------- bf16 helpers (raw bits) ----------
__device__ __forceinline__ unsigned short f2bf(float f) {  // round-to-nearest-even
    unsigned u = __float_as_uint(f);
    return (unsigned short)((u + 0x7fffu + ((u >> 16) & 1u)) >> 16);
}
__device__ __forceinline__ void gload_lds16(const void* g, void* l) {
    __builtin_amdgcn_global_load_lds(
        (const __attribute__((address_space(1))) void*)g,
        (__attribute__((address_space(3))) void*)l, 16, 0, 0);
}

// ---------------------------------------------------------------------------------
// Weight conversion: 8 matrices [1024x1024] fp32 -> bf16.  grid (1024, 8) x 256.
// ---------------------------------------------------------------------------------
struct CvtArgs { const float* src[8]; unsigned short* dst[8]; };

__global__ __launch_bounds__(256) void cvt_kernel(CvtArgs a) {
    const int seg = blockIdx.y;
    const float* s = a.src[seg];
    unsigned short* d = a.dst[seg];
    const size_t i = ((size_t)blockIdx.x * 256 + threadIdx.x) * 4;
    float4 f = *(const float4*)(s + i);
    union { unsigned long long v; unsigned short h[4]; } pk;
    pk.h[0] = f2bf(f.x); pk.h[1] = f2bf(f.y);
    pk.h[2] = f2bf(f.z); pk.h[3] = f2bf(f.w);
    *(unsigned long long*)(d + i) = pk.v;
}

// ---------------------------------------------------------------------------------
// MFMA GEMM: C[m,n] = sum_k A[m,k]*W[n,k] + bias[n]   (M=4096, N=K=1024)
// 128x128 tile, BK=32, 256 thr = 4 waves, each wave 64x64 via 4x4 blocks of
// v_mfma_f32_16x16x32_bf16.  (unchanged from previous round)
// ---------------------------------------------------------------------------------
struct GemmPtrs { const void* x; const unsigned short* w; const float* bias; void* o; };
struct GemmArgs { GemmPtrs p[7]; };

template <bool A_FP32, bool OUT_BF16>
__global__ __launch_bounds__(256) void mfma_gemm(GemmArgs args) {
    const GemmPtrs gp = args.p[blockIdx.z];
    __shared__ unsigned short As[128 * 32];
    __shared__ unsigned short Bs[128 * 32];

    const int tid  = threadIdx.x;
    const int wave = tid >> 6, lane = tid & 63;
    const int row0 = blockIdx.y * 128, col0 = blockIdx.x * 128;
    const int wr = (wave & 1) * 64, wc = (wave >> 1) * 64;
    const int lr = lane & 15;

    const int br1 = tid >> 2,      bq1 = (tid & 3) ^ ((br1 >> 1) & 3);
    const int p2  = tid + 256;
    const int br2 = p2 >> 2,       bq2 = (p2 & 3) ^ ((br2 >> 1) & 3);

    const unsigned short* wp1 = gp.w + (size_t)(col0 + br1) * H_ + bq1 * 8;
    const unsigned short* wp2 = gp.w + (size_t)(col0 + br2) * H_ + bq2 * 8;
    unsigned short* bd1 = Bs + tid * 8;
    unsigned short* bd2 = Bs + (tid + 256) * 8;

    const unsigned short* ap1 =
        (const unsigned short*)gp.x + (size_t)(row0 + br1) * H_ + bq1 * 8;
    const unsigned short* ap2 =
        (const unsigned short*)gp.x + (size_t)(row0 + br2) * H_ + bq2 * 8;
    unsigned short* ad1 = As + tid * 8;
    unsigned short* ad2 = As + (tid + 256) * 8;

    const int ar = tid >> 1, ah = tid & 1, asw = (ar >> 1) & 3;
    const int g0 = (ah * 2) ^ asw, g1 = (ah * 2 + 1) ^ asw;
    const float* ax = (const float*)gp.x + (size_t)(row0 + ar) * H_ + ah * 16;

    const int slot8 = (((lane >> 4) ^ ((lr >> 1) & 3)) << 3);

    f32x4 acc[4][4];
#pragma unroll
    for (int mi = 0; mi < 4; ++mi)
#pragma unroll
        for (int ni = 0; ni < 4; ++ni) acc[mi][ni] = (f32x4)0.f;

    for (int k0 = 0; k0 < H_; k0 += 32) {
        __syncthreads();
        if (A_FP32) {
            float4 f0 = *(const float4*)(ax + k0);
            float4 f1 = *(const float4*)(ax + k0 + 4);
            float4 f2 = *(const float4*)(ax + k0 + 8);
            float4 f3 = *(const float4*)(ax + k0 + 12);
            union { short8 v; unsigned short h[8]; } u0, u1;
            u0.h[0] = f2bf(f0.x); u0.h[1] = f2bf(f0.y);
            u0.h[2] = f2bf(f0.z); u0.h[3] = f2bf(f0.w);
            u0.h[4] = f2bf(f1.x); u0.h[5] = f2bf(f1.y);
            u0.h[6] = f2bf(f1.z); u0.h[7] = f2bf(f1.w);
            u1.h[0] = f2bf(f2.x); u1.h[1] = f2bf(f2.y);
            u1.h[2] = f2bf(f2.z); u1.h[3] = f2bf(f2.w);
            u1.h[4] = f2bf(f3.x); u1.h[5] = f2bf(f3.y);
            u1.h[6] = f2bf(f3.z); u1.h[7] = f2bf(f3.w);
            *(short8*)(As + ar * 32 + g0 * 8) = u0.v;
            *(short8*)(As + ar * 32 + g1 * 8) = u1.v;
        } else {
            gload_lds16(ap1 + k0, ad1);
            gload_lds16(ap2 + k0, ad2);
        }
        gload_lds16(wp1 + k0, bd1);
        gload_lds16(wp2 + k0, bd2);
        __syncthreads();

        short8 af[4], bfr[4];
#pragma unroll
        for (int mi = 0; mi < 4; ++mi)
            af[mi] = *(const short8*)(As + (wr + mi * 16 + lr) * 32 + slot8);
#pragma unroll
        for (int ni = 0; ni < 4; ++ni)
            bfr[ni] = *(const short8*)(Bs + (wc + ni * 16 + lr) * 32 + slot8);
#pragma unroll
        for (int mi = 0; mi < 4; ++mi)
#pragma unroll
            for (int ni = 0; ni < 4; ++ni)
                acc[mi][ni] = __builtin_amdgcn_mfma_f32_16x16x32_bf16(
                    af[mi], bfr[ni], acc[mi][ni], 0, 0, 0);
    }

    float bv[4];
#pragma unroll
    for (int ni = 0; ni < 4; ++ni)
        bv[ni] = gp.bias[col0 + wc + ni * 16 + lr];

#pragma unroll
    for (int mi = 0; mi < 4; ++mi)
#pragma unroll
        for (int r = 0; r < 4; ++r) {
            const int row = row0 + wr + mi * 16 + (lane >> 4) * 4 + r;
#pragma unroll
            for (int ni = 0; ni < 4; ++ni) {
                const int col = col0 + wc + ni * 16 + lr;
                const float v = acc[mi][ni][r] + bv[ni];
                if (OUT_BF16)
                    ((unsigned short*)gp.o)[(size_t)row * H_ + col] = f2bf(v);
                else
                    ((float*)gp.o)[(size_t)row * H_ + col] = v;
            }
        }
}

// ---------------------------------------------------------------------------------
// MFMA flash attention.
//   grid (S/64, B*NH) x 256.  Block: one (b,h), 64 q-rows.  4 waves x 16 rows.
//   Per K-tile (64 keys):
//     - Kc/Kp/Kf staged [64 key][64 d] via global_load_lds w=16, granule-XOR
//       swizzle: source granule q of row r sits at slot q ^ (r&7)  (pre-swizzled
//       global source, linear LDS dest -- m173 pattern).
//     - V staged TRANSPOSED Vt[d][key] (reg->LDS, key-pairs packed as b32),
//       same XOR swizzle -> PV B-frag reads are contiguous ds_read_b128.
//     - scores: acc_c = Q*K^T (content, written raw to amap), acc_s = Qp*Kp^T
//       + Qf*Kf^T.  C layout: col(key)=lane&15, row(q)=(lane>>4)*4+reg.
//     - online softmax per q-row: rows owned by 16-lane groups, __shfl_xor
//       {1,2,4,8} reduces stay in-group.  P -> bf16 -> per-wave LDS (A-frag
//       layout), PV via mfma(P, Vt).
// ---------------------------------------------------------------------------------
__global__ __launch_bounds__(256) void attn_kernel(
        const unsigned short* __restrict__ ws,
        const float* __restrict__ mask,
        float* __restrict__ amap,
        unsigned short* __restrict__ ctxo) {
    const unsigned short* qm0 = ws;                 // q
    const unsigned short* qm1 = ws + 3 * MH_;       // qp
    const unsigned short* qm2 = ws + 5 * MH_;       // qf
    const unsigned short* km0 = ws + 1 * MH_;       // k
    const unsigned short* km1 = ws + 4 * MH_;       // kp
    const unsigned short* km2 = ws + 6 * MH_;       // kf
    const unsigned short* vm  = ws + 2 * MH_;       // v

    __shared__ unsigned short Ks[3][64 * 64];       // 24 KB
    __shared__ unsigned short Vt[64 * 64];          //  8 KB (transposed V)
    __shared__ unsigned short Ps[4][16 * 64];       //  8 KB (per-wave P)

    const int qt  = blockIdx.x;                     // q-tile 0..7
    const int bh  = blockIdx.y;                     // 0..127
    const int b   = bh >> 4, h = bh & 15;
    const int tid = threadIdx.x;
    const int w   = tid >> 6, lane = tid & 63;
    const int lr  = lane & 15, g = lane >> 4;

    // ---- Q fragments in registers (A-layout: row=lane&15, k=(lane>>4)*8+j) ----
    short8 qc[2], qp_[2], qf_[2];
    {
        const int qrow = qt * 64 + w * 16 + lr;
        const size_t base = ((size_t)(b * S_) + qrow) * H_ + h * D_ + g * 8;
#pragma unroll
        for (int kc = 0; kc < 2; ++kc) {
            qc[kc]  = *(const short8*)(qm0 + base + kc * 32);
            qp_[kc] = *(const short8*)(qm1 + base + kc * 32);
            qf_[kc] = *(const short8*)(qm2 + base + kc * 32);
        }
    }

    // ---- staging address precompute ----
    // K tiles: granule p in [0,512): row=p>>3, slot=p&7, src granule = slot^(row&7)
    const int p1 = tid,        r1 = p1 >> 3, s1 = (p1 & 7) ^ (r1 & 7);
    const int p2 = tid + 256,  r2 = p2 >> 3, s2 = (p2 & 7) ^ (r2 & 7);
    const size_t kb1 = ((size_t)(b * S_) + r1) * H_ + h * D_ + s1 * 8;
    const size_t kb2 = ((size_t)(b * S_) + r2) * H_ + h * D_ + s2 * 8;
    unsigned short* kd1[3] = { Ks[0] + p1 * 8, Ks[1] + p1 * 8, Ks[2] + p1 * 8 };
    unsigned short* kd2[3] = { Ks[0] + p2 * 8, Ks[1] + p2 * 8, Ks[2] + p2 * 8 };
    const unsigned short* ksrc[3] = { km0, km1, km2 };

    // Vt: thread handles key pair (vk, vk+1) x 8 d's starting at vdg*8
    const int vk  = (tid & 31) * 2;
    const int vdg = tid >> 5;
    const unsigned short* vp0 = vm + ((size_t)(b * S_) + vk) * H_ + h * D_ + vdg * 8;

    // fragment-read granule slots (kc = k-chunk of 32)
    const int soffA = ((0 + g) ^ (lr & 7)) * 8;     // kc=0
    const int soffB = ((4 + g) ^ (lr & 7)) * 8;     // kc=1

    f32x4 oacc[4];
    float mrun[4], lrun[4];
#pragma unroll
    for (int i = 0; i < 4; ++i) {
        oacc[i] = (f32x4)0.f; mrun[i] = -1e30f; lrun[i] = 0.f;
    }

    for (int t = 0; t < 8; ++t) {
        const size_t koff = (size_t)(t * 64) * H_;
        __syncthreads();                            // prev-tile reads done

        // V -> regs (transpose source)
        union { uint4 u; unsigned short h[8]; } va, vb;
        va.u = *(const uint4*)(vp0 + koff);
        vb.u = *(const uint4*)(vp0 + koff + H_);

        // K tiles -> LDS (async, linear dest, pre-swizzled source)
#pragma unroll
        for (int m = 0; m < 3; ++m) {
            gload_lds16(ksrc[m] + kb1 + koff, kd1[m]);
            gload_lds16(ksrc[m] + kb2 + koff, kd2[m]);
        }

        // Vt writes: Vt[d][key], granule (key>>3)^(d&7), pack key-pair as b32
#pragma unroll
        for (int j = 0; j < 8; ++j) {
            const int d = vdg * 8 + j;
            const unsigned pk = (unsigned)va.h[j] | ((unsigned)vb.h[j] << 16);
            *(unsigned*)(Vt + d * 64 + (((vk >> 3) ^ (d & 7)) * 8) + (vk & 7)) = pk;
        }
        __syncthreads();                            // all staged (drains vmcnt)

        // ---- scores: 24 MFMA / wave ----
        f32x4 accC[4], accS[4];
#pragma unroll
        for (int ni = 0; ni < 4; ++ni) { accC[ni] = (f32x4)0.f; accS[ni] = (f32x4)0.f; }
#pragma unroll
        for (int ni = 0; ni < 4; ++ni) {
            const int rowb = (ni * 16 + lr) * 64;
            short8 c0 = *(const short8*)(Ks[0] + rowb + soffA);
            short8 c1 = *(const short8*)(Ks[0] + rowb + soffB);
            short8 p0 = *(const short8*)(Ks[1] + rowb + soffA);
            short8 p1f = *(const short8*)(Ks[1] + rowb + soffB);
            short8 f0 = *(const short8*)(Ks[2] + rowb + soffA);
            short8 f1 = *(const short8*)(Ks[2] + rowb + soffB);
            accC[ni] = __builtin_amdgcn_mfma_f32_16x16x32_bf16(qc[0], c0, accC[ni], 0, 0, 0);
            accC[ni] = __builtin_amdgcn_mfma_f32_16x16x32_bf16(qc[1], c1, accC[ni], 0, 0, 0);
            accS[ni] = __builtin_amdgcn_mfma_f32_16x16x32_bf16(qp_[0], p0, accS[ni], 0, 0, 0);
            accS[ni] = __builtin_amdgcn_mfma_f32_16x16x32_bf16(qp_[1], p1f, accS[ni], 0, 0, 0);
            accS[ni] = __builtin_amdgcn_mfma_f32_16x16x32_bf16(qf_[0], f0, accS[ni], 0, 0, 0);
            accS[ni] = __builtin_amdgcn_mfma_f32_16x16x32_bf16(qf_[1], f1, accS[ni], 0, 0, 0);
        }

        // ---- amap (raw content) + total scaled+masked scores ----
        const int key0 = t * 64;
        float st[4][4];
#pragma unroll
        for (int ni = 0; ni < 4; ++ni) {
            const int col = key0 + ni * 16 + lr;
#pragma unroll
            for (int r = 0; r < 4; ++r) {
                const int row = qt * 64 + w * 16 + g * 4 + r;
                amap[((size_t)bh * S_ + row) * S_ + col] = accC[ni][r];
                const float mval =
                    mask[(size_t)b * S_ * S_ + (size_t)row * S_ + col];
                st[ni][r] = (accC[ni][r] + accS[ni][r]) * 0.125f + mval;
            }
        }

        // ---- online softmax per q-row (16-lane row groups) ----
#pragma unroll
        for (int r = 0; r < 4; ++r) {
            float tmax = fmaxf(fmaxf(st[0][r], st[1][r]),
                               fmaxf(st[2][r], st[3][r]));
#pragma unroll
            for (int off = 8; off >= 1; off >>= 1)
                tmax = fmaxf(tmax, __shfl_xor(tmax, off));
            const float mnew = fmaxf(mrun[r], tmax);
            const float e0 = __expf(st[0][r] - mnew);
            const float e1 = __expf(st[1][r] - mnew);
            const float e2 = __expf(st[2][r] - mnew);
            const float e3 = __expf(st[3][r] - mnew);
            float esum = (e0 + e1) + (e2 + e3);
#pragma unroll
            for (int off = 8; off >= 1; off >>= 1)
                esum += __shfl_xor(esum, off);
            const float alpha = __expf(mrun[r] - mnew);
            lrun[r] = lrun[r] * alpha + esum;
            mrun[r] = mnew;
#pragma unroll
            for (int nd = 0; nd < 4; ++nd) oacc[nd][r] *= alpha;

            // P -> bf16 -> LDS (A-frag layout, same XOR swizzle)
            const int prow = g * 4 + r;
            unsigned short* pb = Ps[w] + prow * 64;
            const int sw = prow & 7, lh = lr >> 3, lw = lr & 7;
            pb[((0 + lh) ^ sw) * 8 + lw] = f2bf(e0);
            pb[((2 + lh) ^ sw) * 8 + lw] = f2bf(e1);
            pb[((4 + lh) ^ sw) * 8 + lw] = f2bf(e2);
            pb[((6 + lh) ^ sw) * 8 + lw] = f2bf(e3);
        }

        // ---- PV: 8 MFMA / wave.  A=P (row=lr), B=Vt (row=d) ----
#pragma unroll
        for (int kc = 0; kc < 2; ++kc) {
            const int soff = kc ? soffB : soffA;
            short8 pa = *(const short8*)(Ps[w] + lr * 64 + soff);
#pragma unroll
            for (int nd = 0; nd < 4; ++nd) {
                short8 vb2 = *(const short8*)(Vt + (nd * 16 + lr) * 64 + soff);
                oacc[nd] = __builtin_amdgcn_mfma_f32_16x16x32_bf16(
                    pa, vb2, oacc[nd], 0, 0, 0);
            }
        }
    }

    // ---- epilogue: normalize, ctx -> bf16 ----
#pragma unroll
    for (int r = 0; r < 4; ++r) {
        const float inv = 1.0f / lrun[r];
        const int row = qt * 64 + w * 16 + g * 4 + r;
#pragma unroll
        for (int nd = 0; nd < 4; ++nd)
            ctxo[((size_t)(b * S_) + row) * H_ + h * D_ + nd * 16 + lr] =
                f2bf(oacc[nd][r] * inv);
    }
}

// ---------------------------------------------------------------------------------
extern "C" void kernel_launch(void* const* d_in, const int* in_sizes, int n_in,
                              void* d_out, int out_size, void* d_ws, size_t ws_size,
                              hipStream_t stream) {
    // Inputs (fp32): 0 query, 1 key, 2 value, 3 mask, 4 pos_emb, 5 feat_emb,
    // then (W,b) pairs for q,k,v,qp,kp,qf,kf,d at 6..21.
    const float* in[22];
    for (int i = 0; i < 22; ++i) in[i] = (const float*)d_in[i];

    // ws layout: 8 bf16 weights (16 MB) | 7 bf16 projections (56 MB) | bf16 ctx (8 MB)
    unsigned short* wsW = (unsigned short*)d_ws;
    unsigned short* wsP = wsW + 8 * HH_;
    unsigned short* wsC = wsP + 7 * MH_;
    float*          out = (float*)d_out;

    // 1) weights fp32 -> bf16
    CvtArgs ca;
    {
        const int widx[8] = { 6, 8, 10, 12, 14, 16, 18, 20 };
        for (int i = 0; i < 8; ++i) { ca.src[i] = in[widx[i]]; ca.dst[i] = wsW + i * HH_; }
    }
    cvt_kernel<<<dim3(1024, 8), 256, 0, stream>>>(ca);

    // 2) 7 projections (A fp32, out bf16)
    GemmArgs ga;
    ga.p[0] = { in[0], wsW + 0 * HH_, in[7],  wsP + 0 * MH_ };  // q
    ga.p[1] = { in[1], wsW + 1 * HH_, in[9],  wsP + 1 * MH_ };  // k
    ga.p[2] = { in[2], wsW + 2 * HH_, in[11], wsP + 2 * MH_ };  // v
    ga.p[3] = { in[4], wsW + 3 * HH_, in[13], wsP + 3 * MH_ };  // qp
    ga.p[4] = { in[4], wsW + 4 * HH_, in[15], wsP + 4 * MH_ };  // kp
    ga.p[5] = { in[5], wsW + 5 * HH_, in[17], wsP + 5 * MH_ };  // qf
    ga.p[6] = { in[5], wsW + 6 * HH_, in[19], wsP + 6 * MH_ };  // kf
    mfma_gemm<true, true><<<dim3(8, 32, 7), 256, 0, stream>>>(ga);

    // 3) MFMA flash attention: content map -> out + MH_ (fp32), ctx -> wsC (bf16)
    attn_kernel<<<dim3(S_ / 64, B_ * NH_), 256, 0, stream>>>(
        wsP, in[3], out + MH_, wsC);

    // 4) output projection (A bf16, out fp32)
    GemmArgs gf;
    gf.p[0] = { wsC, wsW + 7 * HH_, in[21], out };
    for (int i = 1; i < 7; ++i) gf.p[i] = gf.p[0];
    mfma_gemm<false, false><<<dim3(8, 32, 1), 256, 0, stream>>>(gf);
}

// Round 2
// 428.413 us; speedup vs baseline: 2.4119x; 1.1503x over previous
//
#include <hip/hip_runtime.h>

// Problem constants
#define B_  8
#define S_  512
#define H_  1024
#define NH_ 16
#define D_  64
#define M_  4096                       // B_*S_
#define HH_ ((size_t)H_ * H_)          // 1,048,576  (one weight matrix)
#define MH_ ((size_t)M_ * H_)          // 4,194,304  (one [B,S,H] tensor)

typedef __attribute__((ext_vector_type(8))) short short8;
typedef __attribute__((ext_vector_type(4))) float f32x4;

// ---------- bf16 helpers (raw bits) ----------
__device__ __forceinline__ unsigned short f2bf(float f) {  // round-to-nearest-even
    unsigned u = __float_as_uint(f);
    return (unsigned short)((u + 0x7fffu + ((u >> 16) & 1u)) >> 16);
}
__device__ __forceinline__ void gload_lds16(const void* g, void* l) {
    __builtin_amdgcn_global_load_lds(
        (const __attribute__((address_space(1))) void*)g,
        (__attribute__((address_space(3))) void*)l, 16, 0, 0);
}

// ---------------------------------------------------------------------------------
// fp32 -> bf16 conversion.  28 chunks of 1M elements: 8 weights + 5 activations x 4.
// grid (1024, 28) x 256, 4 elem/thread.
// ---------------------------------------------------------------------------------
struct CvtArgs { const float* src[28]; unsigned short* dst[28]; };

__global__ __launch_bounds__(256) void cvt_kernel(CvtArgs a) {
    const int seg = blockIdx.y;
    const float* s = a.src[seg];
    unsigned short* d = a.dst[seg];
    const size_t i = ((size_t)blockIdx.x * 256 + threadIdx.x) * 4;
    float4 f = *(const float4*)(s + i);
    union { unsigned long long v; unsigned short h[4]; } pk;
    pk.h[0] = f2bf(f.x); pk.h[1] = f2bf(f.y);
    pk.h[2] = f2bf(f.z); pk.h[3] = f2bf(f.w);
    *(unsigned long long*)(d + i) = pk.v;
}

// ---------------------------------------------------------------------------------
// MFMA GEMM: C[m,n] = sum_k A[m,k]*W[n,k] + bias[n]   (M=4096, N=K=1024, bf16 A/W)
// 128x128 tile, BK=32, 4 waves, 4x4 x v_mfma_f32_16x16x32_bf16 per wave.
// Double-buffered LDS, prefetch-before-compute (one __syncthreads per K-step =
// vmcnt(0)+barrier draining the prefetch AFTER the MFMAs).  1D grid with
// bijective XCD-chunk swizzle (nwg % 8 == 0): each XCD owns contiguous (z,y)
// ranges -> A-panel read once per XCD, W resident in its L2.
// ---------------------------------------------------------------------------------
struct GemmPtrs { const unsigned short* x; const unsigned short* w;
                  const float* bias; void* o; };
struct GemmArgs { GemmPtrs p[7]; };

template <bool OUT_BF16>
__global__ __launch_bounds__(256) void mfma_gemm(GemmArgs args, int nwg) {
    const int dd  = blockIdx.x;
    const int cpx = nwg >> 3;
    const int l   = (dd & 7) * cpx + (dd >> 3);     // XCD-chunk swizzle
    const int bz  = l >> 8;                         // 256 blocks per gemm
    const int rem = l & 255;
    const int by  = rem >> 3, bx = rem & 7;         // x fastest: A-panel reuse
    const GemmPtrs gp = args.p[bz];

    __shared__ unsigned short As[2][128 * 32];
    __shared__ unsigned short Bs[2][128 * 32];

    const int tid  = threadIdx.x;
    const int wave = tid >> 6, lane = tid & 63;
    const int row0 = by * 128, col0 = bx * 128;
    const int wr = (wave & 1) * 64, wc = (wave >> 1) * 64;
    const int lr = lane & 15;

    // staging granules p = tid and tid+256:  row = p>>2, slot = p&2..,
    // source k-granule q = slot ^ ((row>>1)&3)  (pre-swizzled source, linear dest)
    const int br1 = tid >> 2,      bq1 = (tid & 3) ^ ((br1 >> 1) & 3);
    const int p2  = tid + 256;
    const int br2 = p2 >> 2,       bq2 = (p2 & 3) ^ ((br2 >> 1) & 3);

    const unsigned short* ap1 = gp.x + (size_t)(row0 + br1) * H_ + bq1 * 8;
    const unsigned short* ap2 = gp.x + (size_t)(row0 + br2) * H_ + bq2 * 8;
    const unsigned short* wp1 = gp.w + (size_t)(col0 + br1) * H_ + bq1 * 8;
    const unsigned short* wp2 = gp.w + (size_t)(col0 + br2) * H_ + bq2 * 8;

    // fragment-read granule slot (same formula for As and Bs)
    const int slot8 = (((lane >> 4) ^ ((lr >> 1) & 3)) << 3);

    f32x4 acc[4][4];
#pragma unroll
    for (int mi = 0; mi < 4; ++mi)
#pragma unroll
        for (int ni = 0; ni < 4; ++ni) acc[mi][ni] = (f32x4)0.f;

    // prologue: stage K-step 0 into buffer 0
    gload_lds16(ap1, As[0] + tid * 8);
    gload_lds16(ap2, As[0] + (tid + 256) * 8);
    gload_lds16(wp1, Bs[0] + tid * 8);
    gload_lds16(wp2, Bs[0] + (tid + 256) * 8);
    __syncthreads();

    int cur = 0;
    for (int t = 0; t < 32; ++t) {
        // prefetch next K-step into the other buffer (hidden under MFMAs)
        if (t < 31) {
            const int k1 = (t + 1) * 32;
            gload_lds16(ap1 + k1, As[cur ^ 1] + tid * 8);
            gload_lds16(ap2 + k1, As[cur ^ 1] + (tid + 256) * 8);
            gload_lds16(wp1 + k1, Bs[cur ^ 1] + tid * 8);
            gload_lds16(wp2 + k1, Bs[cur ^ 1] + (tid + 256) * 8);
        }

        const unsigned short* Ab = As[cur];
        const unsigned short* Bb = Bs[cur];
        short8 af[4], bfr[4];
#pragma unroll
        for (int mi = 0; mi < 4; ++mi)
            af[mi] = *(const short8*)(Ab + (wr + mi * 16 + lr) * 32 + slot8);
#pragma unroll
        for (int ni = 0; ni < 4; ++ni)
            bfr[ni] = *(const short8*)(Bb + (wc + ni * 16 + lr) * 32 + slot8);
#pragma unroll
        for (int mi = 0; mi < 4; ++mi)
#pragma unroll
            for (int ni = 0; ni < 4; ++ni)
                acc[mi][ni] = __builtin_amdgcn_mfma_f32_16x16x32_bf16(
                    af[mi], bfr[ni], acc[mi][ni], 0, 0, 0);

        __syncthreads();        // vmcnt(0)+lgkmcnt(0)+barrier: publish prefetch
        cur ^= 1;
    }

    // epilogue: C/D layout col = lane&15, row = (lane>>4)*4 + reg  [m89/m91]
    float bv[4];
#pragma unroll
    for (int ni = 0; ni < 4; ++ni)
        bv[ni] = gp.bias[col0 + wc + ni * 16 + lr];

#pragma unroll
    for (int mi = 0; mi < 4; ++mi)
#pragma unroll
        for (int r = 0; r < 4; ++r) {
            const int row = row0 + wr + mi * 16 + (lane >> 4) * 4 + r;
#pragma unroll
            for (int ni = 0; ni < 4; ++ni) {
                const int col = col0 + wc + ni * 16 + lr;
                const float v = acc[mi][ni][r] + bv[ni];
                if (OUT_BF16)
                    ((unsigned short*)gp.o)[(size_t)row * H_ + col] = f2bf(v);
                else
                    ((float*)gp.o)[(size_t)row * H_ + col] = v;
            }
        }
}

// ---------------------------------------------------------------------------------
// MFMA flash attention.  1D grid 1024 with XCD-chunk swizzle so the 8 q-tile
// blocks of one (b,h) land on the same XCD (K/V/mask reuse in its L2).
// Structure unchanged from previous round (verified).
// ---------------------------------------------------------------------------------
__global__ __launch_bounds__(256) void attn_kernel(
        const unsigned short* __restrict__ ws,
        const float* __restrict__ mask,
        float* __restrict__ amap,
        unsigned short* __restrict__ ctxo) {
    const unsigned short* qm0 = ws;                 // q
    const unsigned short* qm1 = ws + 3 * MH_;       // qp
    const unsigned short* qm2 = ws + 5 * MH_;       // qf
    const unsigned short* km0 = ws + 1 * MH_;       // k
    const unsigned short* km1 = ws + 4 * MH_;       // kp
    const unsigned short* km2 = ws + 6 * MH_;       // kf
    const unsigned short* vm  = ws + 2 * MH_;       // v

    __shared__ unsigned short Ks[3][64 * 64];       // 24 KB
    __shared__ unsigned short Vt[64 * 64];          //  8 KB (transposed V)
    __shared__ unsigned short Ps[4][16 * 64];       //  8 KB (per-wave P)

    const int blk = blockIdx.x;                     // 0..1023
    const int l   = (blk & 7) * 128 + (blk >> 3);   // XCD-chunk swizzle
    const int qt  = l & 7;                          // q-tile 0..7
    const int bh  = l >> 3;                         // 0..127
    const int b   = bh >> 4, h = bh & 15;
    const int tid = threadIdx.x;
    const int w   = tid >> 6, lane = tid & 63;
    const int lr  = lane & 15, g = lane >> 4;

    // ---- Q fragments in registers (A-layout: row=lane&15, k=(lane>>4)*8+j) ----
    short8 qc[2], qp_[2], qf_[2];
    {
        const int qrow = qt * 64 + w * 16 + lr;
        const size_t base = ((size_t)(b * S_) + qrow) * H_ + h * D_ + g * 8;
#pragma unroll
        for (int kc = 0; kc < 2; ++kc) {
            qc[kc]  = *(const short8*)(qm0 + base + kc * 32);
            qp_[kc] = *(const short8*)(qm1 + base + kc * 32);
            qf_[kc] = *(const short8*)(qm2 + base + kc * 32);
        }
    }

    // ---- staging address precompute ----
    const int p1 = tid,        r1 = p1 >> 3, s1 = (p1 & 7) ^ (r1 & 7);
    const int p2 = tid + 256,  r2 = p2 >> 3, s2 = (p2 & 7) ^ (r2 & 7);
    const size_t kb1 = ((size_t)(b * S_) + r1) * H_ + h * D_ + s1 * 8;
    const size_t kb2 = ((size_t)(b * S_) + r2) * H_ + h * D_ + s2 * 8;
    unsigned short* kd1[3] = { Ks[0] + p1 * 8, Ks[1] + p1 * 8, Ks[2] + p1 * 8 };
    unsigned short* kd2[3] = { Ks[0] + p2 * 8, Ks[1] + p2 * 8, Ks[2] + p2 * 8 };
    const unsigned short* ksrc[3] = { km0, km1, km2 };

    const int vk  = (tid & 31) * 2;
    const int vdg = tid >> 5;
    const unsigned short* vp0 = vm + ((size_t)(b * S_) + vk) * H_ + h * D_ + vdg * 8;

    const int soffA = ((0 + g) ^ (lr & 7)) * 8;     // kc=0
    const int soffB = ((4 + g) ^ (lr & 7)) * 8;     // kc=1

    f32x4 oacc[4];
    float mrun[4], lrun[4];
#pragma unroll
    for (int i = 0; i < 4; ++i) {
        oacc[i] = (f32x4)0.f; mrun[i] = -1e30f; lrun[i] = 0.f;
    }

    for (int t = 0; t < 8; ++t) {
        const size_t koff = (size_t)(t * 64) * H_;
        __syncthreads();                            // prev-tile reads done

        union { uint4 u; unsigned short h[8]; } va, vb;
        va.u = *(const uint4*)(vp0 + koff);
        vb.u = *(const uint4*)(vp0 + koff + H_);

#pragma unroll
        for (int m = 0; m < 3; ++m) {
            gload_lds16(ksrc[m] + kb1 + koff, kd1[m]);
            gload_lds16(ksrc[m] + kb2 + koff, kd2[m]);
        }

#pragma unroll
        for (int j = 0; j < 8; ++j) {
            const int d = vdg * 8 + j;
            const unsigned pk = (unsigned)va.h[j] | ((unsigned)vb.h[j] << 16);
            *(unsigned*)(Vt + d * 64 + (((vk >> 3) ^ (d & 7)) * 8) + (vk & 7)) = pk;
        }
        __syncthreads();                            // all staged (drains vmcnt)

        // ---- scores: 24 MFMA / wave ----
        f32x4 accC[4], accS[4];
#pragma unroll
        for (int ni = 0; ni < 4; ++ni) { accC[ni] = (f32x4)0.f; accS[ni] = (f32x4)0.f; }
#pragma unroll
        for (int ni = 0; ni < 4; ++ni) {
            const int rowb = (ni * 16 + lr) * 64;
            short8 c0 = *(const short8*)(Ks[0] + rowb + soffA);
            short8 c1 = *(const short8*)(Ks[0] + rowb + soffB);
            short8 p0 = *(const short8*)(Ks[1] + rowb + soffA);
            short8 p1f = *(const short8*)(Ks[1] + rowb + soffB);
            short8 f0 = *(const short8*)(Ks[2] + rowb + soffA);
            short8 f1 = *(const short8*)(Ks[2] + rowb + soffB);
            accC[ni] = __builtin_amdgcn_mfma_f32_16x16x32_bf16(qc[0], c0, accC[ni], 0, 0, 0);
            accC[ni] = __builtin_amdgcn_mfma_f32_16x16x32_bf16(qc[1], c1, accC[ni], 0, 0, 0);
            accS[ni] = __builtin_amdgcn_mfma_f32_16x16x32_bf16(qp_[0], p0, accS[ni], 0, 0, 0);
            accS[ni] = __builtin_amdgcn_mfma_f32_16x16x32_bf16(qp_[1], p1f, accS[ni], 0, 0, 0);
            accS[ni] = __builtin_amdgcn_mfma_f32_16x16x32_bf16(qf_[0], f0, accS[ni], 0, 0, 0);
            accS[ni] = __builtin_amdgcn_mfma_f32_16x16x32_bf16(qf_[1], f1, accS[ni], 0, 0, 0);
        }

        // ---- amap (raw content) + total scaled+masked scores ----
        const int key0 = t * 64;
        float st[4][4];
#pragma unroll
        for (int ni = 0; ni < 4; ++ni) {
            const int col = key0 + ni * 16 + lr;
#pragma unroll
            for (int r = 0; r < 4; ++r) {
                const int row = qt * 64 + w * 16 + g * 4 + r;
                amap[((size_t)bh * S_ + row) * S_ + col] = accC[ni][r];
                const float mval =
                    mask[(size_t)b * S_ * S_ + (size_t)row * S_ + col];
                st[ni][r] = (accC[ni][r] + accS[ni][r]) * 0.125f + mval;
            }
        }

        // ---- online softmax per q-row (16-lane row groups) ----
#pragma unroll
        for (int r = 0; r < 4; ++r) {
            float tmax = fmaxf(fmaxf(st[0][r], st[1][r]),
                               fmaxf(st[2][r], st[3][r]));
#pragma unroll
            for (int off = 8; off >= 1; off >>= 1)
                tmax = fmaxf(tmax, __shfl_xor(tmax, off));
            const float mnew = fmaxf(mrun[r], tmax);
            const float e0 = __expf(st[0][r] - mnew);
            const float e1 = __expf(st[1][r] - mnew);
            const float e2 = __expf(st[2][r] - mnew);
            const float e3 = __expf(st[3][r] - mnew);
            float esum = (e0 + e1) + (e2 + e3);
#pragma unroll
            for (int off = 8; off >= 1; off >>= 1)
                esum += __shfl_xor(esum, off);
            const float alpha = __expf(mrun[r] - mnew);
            lrun[r] = lrun[r] * alpha + esum;
            mrun[r] = mnew;
#pragma unroll
            for (int nd = 0; nd < 4; ++nd) oacc[nd][r] *= alpha;

            const int prow = g * 4 + r;
            unsigned short* pb = Ps[w] + prow * 64;
            const int sw = prow & 7, lh = lr >> 3, lw = lr & 7;
            pb[((0 + lh) ^ sw) * 8 + lw] = f2bf(e0);
            pb[((2 + lh) ^ sw) * 8 + lw] = f2bf(e1);
            pb[((4 + lh) ^ sw) * 8 + lw] = f2bf(e2);
            pb[((6 + lh) ^ sw) * 8 + lw] = f2bf(e3);
        }

        // ---- PV: 8 MFMA / wave ----
#pragma unroll
        for (int kc = 0; kc < 2; ++kc) {
            const int soff = kc ? soffB : soffA;
            short8 pa = *(const short8*)(Ps[w] + lr * 64 + soff);
#pragma unroll
            for (int nd = 0; nd < 4; ++nd) {
                short8 vb2 = *(const short8*)(Vt + (nd * 16 + lr) * 64 + soff);
                oacc[nd] = __builtin_amdgcn_mfma_f32_16x16x32_bf16(
                    pa, vb2, oacc[nd], 0, 0, 0);
            }
        }
    }

    // ---- epilogue ----
#pragma unroll
    for (int r = 0; r < 4; ++r) {
        const float inv = 1.0f / lrun[r];
        const int row = qt * 64 + w * 16 + g * 4 + r;
#pragma unroll
        for (int nd = 0; nd < 4; ++nd)
            ctxo[((size_t)(b * S_) + row) * H_ + h * D_ + nd * 16 + lr] =
                f2bf(oacc[nd][r] * inv);
    }
}

// ---------------------------------------------------------------------------------
extern "C" void kernel_launch(void* const* d_in, const int* in_sizes, int n_in,
                              void* d_out, int out_size, void* d_ws, size_t ws_size,
                              hipStream_t stream) {
    // Inputs (fp32): 0 query, 1 key, 2 value, 3 mask, 4 pos_emb, 5 feat_emb,
    // then (W,b) pairs for q,k,v,qp,kp,qf,kf,d at 6..21.
    const float* in[22];
    for (int i = 0; i < 22; ++i) in[i] = (const float*)d_in[i];

    // ws layout: 8 bf16 weights (16 MB) | 7 bf16 projections (56 MB) |
    //            bf16 ctx (8 MB) | 5 bf16 activations (40 MB)
    unsigned short* wsW = (unsigned short*)d_ws;
    unsigned short* wsP = wsW + 8 * HH_;
    unsigned short* wsC = wsP + 7 * MH_;
    unsigned short* wsA = wsC + 1 * MH_;
    float*          out = (float*)d_out;

    // 1) fp32 -> bf16: 8 weights + 5 activations (q,k,v,pos,feat)
    CvtArgs ca;
    {
        int ci = 0;
        const int widx[8] = { 6, 8, 10, 12, 14, 16, 18, 20 };
        for (int i = 0; i < 8; ++i, ++ci) {
            ca.src[ci] = in[widx[i]];
            ca.dst[ci] = wsW + i * HH_;
        }
        const int aidx[5] = { 0, 1, 2, 4, 5 };
        for (int i = 0; i < 5; ++i)
            for (int c = 0; c < 4; ++c, ++ci) {
                ca.src[ci] = in[aidx[i]] + (size_t)c * HH_;
                ca.dst[ci] = wsA + i * MH_ + (size_t)c * HH_;
            }
    }
    cvt_kernel<<<dim3(1024, 28), 256, 0, stream>>>(ca);

    // 2) 7 projections (A bf16, out bf16)
    GemmArgs ga;
    ga.p[0] = { wsA + 0 * MH_, wsW + 0 * HH_, in[7],  wsP + 0 * MH_ };  // q
    ga.p[1] = { wsA + 1 * MH_, wsW + 1 * HH_, in[9],  wsP + 1 * MH_ };  // k
    ga.p[2] = { wsA + 2 * MH_, wsW + 2 * HH_, in[11], wsP + 2 * MH_ };  // v
    ga.p[3] = { wsA + 3 * MH_, wsW + 3 * HH_, in[13], wsP + 3 * MH_ };  // qp
    ga.p[4] = { wsA + 3 * MH_, wsW + 4 * HH_, in[15], wsP + 4 * MH_ };  // kp
    ga.p[5] = { wsA + 4 * MH_, wsW + 5 * HH_, in[17], wsP + 5 * MH_ };  // qf
    ga.p[6] = { wsA + 4 * MH_, wsW + 6 * HH_, in[19], wsP + 6 * MH_ };  // kf
    mfma_gemm<true><<<dim3(1792), 256, 0, stream>>>(ga, 1792);

    // 3) MFMA flash attention: content map -> out + MH_ (fp32), ctx -> wsC (bf16)
    attn_kernel<<<dim3(1024), 256, 0, stream>>>(wsP, in[3], out + MH_, wsC);

    // 4) output projection (A bf16, out fp32)
    GemmArgs gf;
    gf.p[0] = { wsC, wsW + 7 * HH_, in[21], out };
    for (int i = 1; i < 7; ++i) gf.p[i] = gf.p[0];
    mfma_gemm<false><<<dim3(256), 256, 0, stream>>>(gf, 256);
}

// Round 3
// 407.525 us; speedup vs baseline: 2.5355x; 1.0513x over previous
//
#include <hip/hip_runtime.h>

// Problem constants
#define B_  8
#define S_  512
#define H_  1024
#define NH_ 16
#define D_  64
#define M_  4096                       // B_*S_
#define HH_ ((size_t)H_ * H_)          // 1,048,576  (one weight matrix)
#define MH_ ((size_t)M_ * H_)          // 4,194,304  (one [B,S,H] tensor)

typedef __attribute__((ext_vector_type(8))) short short8;
typedef __attribute__((ext_vector_type(4))) float f32x4;

// ---------- bf16 helpers (raw bits) ----------
__device__ __forceinline__ unsigned short f2bf(float f) {  // round-to-nearest-even
    unsigned u = __float_as_uint(f);
    return (unsigned short)((u + 0x7fffu + ((u >> 16) & 1u)) >> 16);
}
__device__ __forceinline__ void gload_lds16(const void* g, void* l) {
    __builtin_amdgcn_global_load_lds(
        (const __attribute__((address_space(1))) void*)g,
        (__attribute__((address_space(3))) void*)l, 16, 0, 0);
}

// ---------------------------------------------------------------------------------
// fp32 -> bf16 conversion.  28 chunks of 1M elements: 8 weights + 5 activations x 4.
// grid (1024, 28) x 256, 4 elem/thread.
// ---------------------------------------------------------------------------------
struct CvtArgs { const float* src[28]; unsigned short* dst[28]; };

__global__ __launch_bounds__(256) void cvt_kernel(CvtArgs a) {
    const int seg = blockIdx.y;
    const float* s = a.src[seg];
    unsigned short* d = a.dst[seg];
    const size_t i = ((size_t)blockIdx.x * 256 + threadIdx.x) * 4;
    float4 f = *(const float4*)(s + i);
    union { unsigned long long v; unsigned short h[4]; } pk;
    pk.h[0] = f2bf(f.x); pk.h[1] = f2bf(f.y);
    pk.h[2] = f2bf(f.z); pk.h[3] = f2bf(f.w);
    *(unsigned long long*)(d + i) = pk.v;
}

// ---------------------------------------------------------------------------------
// MFMA GEMM: C[m,n] = sum_k A[m,k]*W[n,k] + bias[n]   (M=4096, N=K=1024, bf16 A/W)
// 128x128 tile, BK=32, 4 waves, 4x4 x v_mfma_f32_16x16x32_bf16 per wave.
// Ring-4 LDS (64 KB), stage tile t+3 while computing tile t; raw s_barrier with
// COUNTED s_waitcnt vmcnt(8) once per K-step (2 tiles stay in flight, never
// drained to 0 in steady state -- T4).  Full 32-step unroll: all global/LDS
// offsets are compile-time immediates (no per-iter VALU address math).
// Slot-reuse safety: stage target slot (t+3)&3 == (t-1)&3, whose last reader
// finished before the (t-1)-end barrier; vmcnt(8)+barrier at end of step t
// guarantees tile t+1 fully resident for step t+1.
// 1D grid, bijective XCD-chunk swizzle (nwg % 8 == 0).
// ---------------------------------------------------------------------------------
struct GemmPtrs { const unsigned short* x; const unsigned short* w;
                  const float* bias; void* o; };
struct GemmArgs { GemmPtrs p[7]; };

template <bool OUT_BF16>
__global__ __launch_bounds__(256) void mfma_gemm(GemmArgs args, int nwg) {
    const int dd  = blockIdx.x;
    const int cpx = nwg >> 3;
    const int l   = (dd & 7) * cpx + (dd >> 3);     // XCD-chunk swizzle
    const int bz  = l >> 8;                         // 256 blocks per gemm
    const int rem = l & 255;
    const int by  = rem >> 3, bx = rem & 7;         // x fastest: A-panel reuse
    const GemmPtrs gp = args.p[bz];

    __shared__ unsigned short As[4][128 * 32];      // 32 KB (ring of 4 K-tiles)
    __shared__ unsigned short Bs[4][128 * 32];      // 32 KB

    const int tid  = threadIdx.x;
    const int wave = tid >> 6, lane = tid & 63;
    const int row0 = by * 128, col0 = bx * 128;
    const int wr = (wave & 1) * 64, wc = (wave >> 1) * 64;
    const int lr = lane & 15;

    // staging granules p = tid and tid+256:  row = p>>2, slot = p&3,
    // source k-granule q = slot ^ ((row>>1)&3)  (pre-swizzled source, linear dest)
    const int br1 = tid >> 2,      bq1 = (tid & 3) ^ ((br1 >> 1) & 3);
    const int p2  = tid + 256;
    const int br2 = p2 >> 2,       bq2 = (p2 & 3) ^ ((br2 >> 1) & 3);

    const unsigned short* ap1 = gp.x + (size_t)(row0 + br1) * H_ + bq1 * 8;
    const unsigned short* ap2 = gp.x + (size_t)(row0 + br2) * H_ + bq2 * 8;
    const unsigned short* wp1 = gp.w + (size_t)(col0 + br1) * H_ + bq1 * 8;
    const unsigned short* wp2 = gp.w + (size_t)(col0 + br2) * H_ + bq2 * 8;

    // fragment-read granule slot (same formula for As and Bs)
    const int slot8 = (((lane >> 4) ^ ((lr >> 1) & 3)) << 3);

    f32x4 acc[4][4];
#pragma unroll
    for (int mi = 0; mi < 4; ++mi)
#pragma unroll
        for (int ni = 0; ni < 4; ++ni) acc[mi][ni] = (f32x4)0.f;

    // prologue: stage K-tiles 0,1,2 into ring slots 0,1,2 (12 loads/thread-group)
#pragma unroll
    for (int pt = 0; pt < 3; ++pt) {
        const int kk = pt * 32;
        gload_lds16(ap1 + kk, As[pt] + tid * 8);
        gload_lds16(ap2 + kk, As[pt] + (tid + 256) * 8);
        gload_lds16(wp1 + kk, Bs[pt] + tid * 8);
        gload_lds16(wp2 + kk, Bs[pt] + (tid + 256) * 8);
    }
    asm volatile("s_waitcnt vmcnt(8)" ::: "memory");   // tile 0 resident
    __builtin_amdgcn_sched_barrier(0);
    __builtin_amdgcn_s_barrier();

#pragma unroll
    for (int t = 0; t < 32; ++t) {
        // ---- fragment reads from ring slot t&3 (all offsets compile-time) ----
        const unsigned short* Ab = As[t & 3];
        const unsigned short* Bb = Bs[t & 3];
        short8 af[4], bfr[4];
#pragma unroll
        for (int mi = 0; mi < 4; ++mi)
            af[mi] = *(const short8*)(Ab + (wr + mi * 16 + lr) * 32 + slot8);
#pragma unroll
        for (int ni = 0; ni < 4; ++ni)
            bfr[ni] = *(const short8*)(Bb + (wc + ni * 16 + lr) * 32 + slot8);

        // ---- stage K-tile t+3 into slot (t+3)&3 (== (t-1)&3, safely retired) ----
        if (t + 3 < 32) {
            const int kk = (t + 3) * 32;
            const int s  = (t + 3) & 3;
            gload_lds16(ap1 + kk, As[s] + tid * 8);
            gload_lds16(ap2 + kk, As[s] + (tid + 256) * 8);
            gload_lds16(wp1 + kk, Bs[s] + tid * 8);
            gload_lds16(wp2 + kk, Bs[s] + (tid + 256) * 8);
        }

        // ---- 16 MFMA (compiler inserts lgkmcnt for the frag deps) ----
        __builtin_amdgcn_s_setprio(1);
#pragma unroll
        for (int mi = 0; mi < 4; ++mi)
#pragma unroll
            for (int ni = 0; ni < 4; ++ni)
                acc[mi][ni] = __builtin_amdgcn_mfma_f32_16x16x32_bf16(
                    af[mi], bfr[ni], acc[mi][ni], 0, 0, 0);
        __builtin_amdgcn_s_setprio(0);

        // ---- counted wait: tile t+1 resident, tiles t+2/t+3 stay in flight ----
        if (t < 29)       asm volatile("s_waitcnt vmcnt(8)" ::: "memory");
        else if (t == 29) asm volatile("s_waitcnt vmcnt(4)" ::: "memory");
        else if (t == 30) asm volatile("s_waitcnt vmcnt(0)" ::: "memory");
        if (t < 31) {
            __builtin_amdgcn_sched_barrier(0);
            __builtin_amdgcn_s_barrier();
        }
    }

    // epilogue: C/D layout col = lane&15, row = (lane>>4)*4 + reg  [m89/m91]
    float bv[4];
#pragma unroll
    for (int ni = 0; ni < 4; ++ni)
        bv[ni] = gp.bias[col0 + wc + ni * 16 + lr];

#pragma unroll
    for (int mi = 0; mi < 4; ++mi)
#pragma unroll
        for (int r = 0; r < 4; ++r) {
            const int row = row0 + wr + mi * 16 + (lane >> 4) * 4 + r;
#pragma unroll
            for (int ni = 0; ni < 4; ++ni) {
                const int col = col0 + wc + ni * 16 + lr;
                const float v = acc[mi][ni][r] + bv[ni];
                if (OUT_BF16)
                    ((unsigned short*)gp.o)[(size_t)row * H_ + col] = f2bf(v);
                else
                    ((float*)gp.o)[(size_t)row * H_ + col] = v;
            }
        }
}

// ---------------------------------------------------------------------------------
// MFMA flash attention (verified round-2 structure, unchanged).
// ---------------------------------------------------------------------------------
__global__ __launch_bounds__(256) void attn_kernel(
        const unsigned short* __restrict__ ws,
        const float* __restrict__ mask,
        float* __restrict__ amap,
        unsigned short* __restrict__ ctxo) {
    const unsigned short* qm0 = ws;                 // q
    const unsigned short* qm1 = ws + 3 * MH_;       // qp
    const unsigned short* qm2 = ws + 5 * MH_;       // qf
    const unsigned short* km0 = ws + 1 * MH_;       // k
    const unsigned short* km1 = ws + 4 * MH_;       // kp
    const unsigned short* km2 = ws + 6 * MH_;       // kf
    const unsigned short* vm  = ws + 2 * MH_;       // v

    __shared__ unsigned short Ks[3][64 * 64];       // 24 KB
    __shared__ unsigned short Vt[64 * 64];          //  8 KB (transposed V)
    __shared__ unsigned short Ps[4][16 * 64];       //  8 KB (per-wave P)

    const int blk = blockIdx.x;                     // 0..1023
    const int l   = (blk & 7) * 128 + (blk >> 3);   // XCD-chunk swizzle
    const int qt  = l & 7;                          // q-tile 0..7
    const int bh  = l >> 3;                         // 0..127
    const int b   = bh >> 4, h = bh & 15;
    const int tid = threadIdx.x;
    const int w   = tid >> 6, lane = tid & 63;
    const int lr  = lane & 15, g = lane >> 4;

    // ---- Q fragments in registers (A-layout: row=lane&15, k=(lane>>4)*8+j) ----
    short8 qc[2], qp_[2], qf_[2];
    {
        const int qrow = qt * 64 + w * 16 + lr;
        const size_t base = ((size_t)(b * S_) + qrow) * H_ + h * D_ + g * 8;
#pragma unroll
        for (int kc = 0; kc < 2; ++kc) {
            qc[kc]  = *(const short8*)(qm0 + base + kc * 32);
            qp_[kc] = *(const short8*)(qm1 + base + kc * 32);
            qf_[kc] = *(const short8*)(qm2 + base + kc * 32);
        }
    }

    // ---- staging address precompute ----
    const int p1 = tid,        r1 = p1 >> 3, s1 = (p1 & 7) ^ (r1 & 7);
    const int p2 = tid + 256,  r2 = p2 >> 3, s2 = (p2 & 7) ^ (r2 & 7);
    const size_t kb1 = ((size_t)(b * S_) + r1) * H_ + h * D_ + s1 * 8;
    const size_t kb2 = ((size_t)(b * S_) + r2) * H_ + h * D_ + s2 * 8;
    unsigned short* kd1[3] = { Ks[0] + p1 * 8, Ks[1] + p1 * 8, Ks[2] + p1 * 8 };
    unsigned short* kd2[3] = { Ks[0] + p2 * 8, Ks[1] + p2 * 8, Ks[2] + p2 * 8 };
    const unsigned short* ksrc[3] = { km0, km1, km2 };

    const int vk  = (tid & 31) * 2;
    const int vdg = tid >> 5;
    const unsigned short* vp0 = vm + ((size_t)(b * S_) + vk) * H_ + h * D_ + vdg * 8;

    const int soffA = ((0 + g) ^ (lr & 7)) * 8;     // kc=0
    const int soffB = ((4 + g) ^ (lr & 7)) * 8;     // kc=1

    f32x4 oacc[4];
    float mrun[4], lrun[4];
#pragma unroll
    for (int i = 0; i < 4; ++i) {
        oacc[i] = (f32x4)0.f; mrun[i] = -1e30f; lrun[i] = 0.f;
    }

    for (int t = 0; t < 8; ++t) {
        const size_t koff = (size_t)(t * 64) * H_;
        __syncthreads();                            // prev-tile reads done

        union { uint4 u; unsigned short h[8]; } va, vb;
        va.u = *(const uint4*)(vp0 + koff);
        vb.u = *(const uint4*)(vp0 + koff + H_);

#pragma unroll
        for (int m = 0; m < 3; ++m) {
            gload_lds16(ksrc[m] + kb1 + koff, kd1[m]);
            gload_lds16(ksrc[m] + kb2 + koff, kd2[m]);
        }

#pragma unroll
        for (int j = 0; j < 8; ++j) {
            const int d = vdg * 8 + j;
            const unsigned pk = (unsigned)va.h[j] | ((unsigned)vb.h[j] << 16);
            *(unsigned*)(Vt + d * 64 + (((vk >> 3) ^ (d & 7)) * 8) + (vk & 7)) = pk;
        }
        __syncthreads();                            // all staged (drains vmcnt)

        // ---- scores: 24 MFMA / wave ----
        f32x4 accC[4], accS[4];
#pragma unroll
        for (int ni = 0; ni < 4; ++ni) { accC[ni] = (f32x4)0.f; accS[ni] = (f32x4)0.f; }
#pragma unroll
        for (int ni = 0; ni < 4; ++ni) {
            const int rowb = (ni * 16 + lr) * 64;
            short8 c0 = *(const short8*)(Ks[0] + rowb + soffA);
            short8 c1 = *(const short8*)(Ks[0] + rowb + soffB);
            short8 p0 = *(const short8*)(Ks[1] + rowb + soffA);
            short8 p1f = *(const short8*)(Ks[1] + rowb + soffB);
            short8 f0 = *(const short8*)(Ks[2] + rowb + soffA);
            short8 f1 = *(const short8*)(Ks[2] + rowb + soffB);
            accC[ni] = __builtin_amdgcn_mfma_f32_16x16x32_bf16(qc[0], c0, accC[ni], 0, 0, 0);
            accC[ni] = __builtin_amdgcn_mfma_f32_16x16x32_bf16(qc[1], c1, accC[ni], 0, 0, 0);
            accS[ni] = __builtin_amdgcn_mfma_f32_16x16x32_bf16(qp_[0], p0, accS[ni], 0, 0, 0);
            accS[ni] = __builtin_amdgcn_mfma_f32_16x16x32_bf16(qp_[1], p1f, accS[ni], 0, 0, 0);
            accS[ni] = __builtin_amdgcn_mfma_f32_16x16x32_bf16(qf_[0], f0, accS[ni], 0, 0, 0);
            accS[ni] = __builtin_amdgcn_mfma_f32_16x16x32_bf16(qf_[1], f1, accS[ni], 0, 0, 0);
        }

        // ---- amap (raw content) + total scaled+masked scores ----
        const int key0 = t * 64;
        float st[4][4];
#pragma unroll
        for (int ni = 0; ni < 4; ++ni) {
            const int col = key0 + ni * 16 + lr;
#pragma unroll
            for (int r = 0; r < 4; ++r) {
                const int row = qt * 64 + w * 16 + g * 4 + r;
                amap[((size_t)bh * S_ + row) * S_ + col] = accC[ni][r];
                const float mval =
                    mask[(size_t)b * S_ * S_ + (size_t)row * S_ + col];
                st[ni][r] = (accC[ni][r] + accS[ni][r]) * 0.125f + mval;
            }
        }

        // ---- online softmax per q-row (16-lane row groups) ----
#pragma unroll
        for (int r = 0; r < 4; ++r) {
            float tmax = fmaxf(fmaxf(st[0][r], st[1][r]),
                               fmaxf(st[2][r], st[3][r]));
#pragma unroll
            for (int off = 8; off >= 1; off >>= 1)
                tmax = fmaxf(tmax, __shfl_xor(tmax, off));
            const float mnew = fmaxf(mrun[r], tmax);
            const float e0 = __expf(st[0][r] - mnew);
            const float e1 = __expf(st[1][r] - mnew);
            const float e2 = __expf(st[2][r] - mnew);
            const float e3 = __expf(st[3][r] - mnew);
            float esum = (e0 + e1) + (e2 + e3);
#pragma unroll
            for (int off = 8; off >= 1; off >>= 1)
                esum += __shfl_xor(esum, off);
            const float alpha = __expf(mrun[r] - mnew);
            lrun[r] = lrun[r] * alpha + esum;
            mrun[r] = mnew;
#pragma unroll
            for (int nd = 0; nd < 4; ++nd) oacc[nd][r] *= alpha;

            const int prow = g * 4 + r;
            unsigned short* pb = Ps[w] + prow * 64;
            const int sw = prow & 7, lh = lr >> 3, lw = lr & 7;
            pb[((0 + lh) ^ sw) * 8 + lw] = f2bf(e0);
            pb[((2 + lh) ^ sw) * 8 + lw] = f2bf(e1);
            pb[((4 + lh) ^ sw) * 8 + lw] = f2bf(e2);
            pb[((6 + lh) ^ sw) * 8 + lw] = f2bf(e3);
        }

        // ---- PV: 8 MFMA / wave ----
#pragma unroll
        for (int kc = 0; kc < 2; ++kc) {
            const int soff = kc ? soffB : soffA;
            short8 pa = *(const short8*)(Ps[w] + lr * 64 + soff);
#pragma unroll
            for (int nd = 0; nd < 4; ++nd) {
                short8 vb2 = *(const short8*)(Vt + (nd * 16 + lr) * 64 + soff);
                oacc[nd] = __builtin_amdgcn_mfma_f32_16x16x32_bf16(
                    pa, vb2, oacc[nd], 0, 0, 0);
            }
        }
    }

    // ---- epilogue ----
#pragma unroll
    for (int r = 0; r < 4; ++r) {
        const float inv = 1.0f / lrun[r];
        const int row = qt * 64 + w * 16 + g * 4 + r;
#pragma unroll
        for (int nd = 0; nd < 4; ++nd)
            ctxo[((size_t)(b * S_) + row) * H_ + h * D_ + nd * 16 + lr] =
                f2bf(oacc[nd][r] * inv);
    }
}

// ---------------------------------------------------------------------------------
extern "C" void kernel_launch(void* const* d_in, const int* in_sizes, int n_in,
                              void* d_out, int out_size, void* d_ws, size_t ws_size,
                              hipStream_t stream) {
    // Inputs (fp32): 0 query, 1 key, 2 value, 3 mask, 4 pos_emb, 5 feat_emb,
    // then (W,b) pairs for q,k,v,qp,kp,qf,kf,d at 6..21.
    const float* in[22];
    for (int i = 0; i < 22; ++i) in[i] = (const float*)d_in[i];

    // ws layout: 8 bf16 weights (16 MB) | 7 bf16 projections (56 MB) |
    //            bf16 ctx (8 MB) | 5 bf16 activations (40 MB)
    unsigned short* wsW = (unsigned short*)d_ws;
    unsigned short* wsP = wsW + 8 * HH_;
    unsigned short* wsC = wsP + 7 * MH_;
    unsigned short* wsA = wsC + 1 * MH_;
    float*          out = (float*)d_out;

    // 1) fp32 -> bf16: 8 weights + 5 activations (q,k,v,pos,feat)
    CvtArgs ca;
    {
        int ci = 0;
        const int widx[8] = { 6, 8, 10, 12, 14, 16, 18, 20 };
        for (int i = 0; i < 8; ++i, ++ci) {
            ca.src[ci] = in[widx[i]];
            ca.dst[ci] = wsW + i * HH_;
        }
        const int aidx[5] = { 0, 1, 2, 4, 5 };
        for (int i = 0; i < 5; ++i)
            for (int c = 0; c < 4; ++c, ++ci) {
                ca.src[ci] = in[aidx[i]] + (size_t)c * HH_;
                ca.dst[ci] = wsA + i * MH_ + (size_t)c * HH_;
            }
    }
    cvt_kernel<<<dim3(1024, 28), 256, 0, stream>>>(ca);

    // 2) 7 projections (A bf16, out bf16)
    GemmArgs ga;
    ga.p[0] = { wsA + 0 * MH_, wsW + 0 * HH_, in[7],  wsP + 0 * MH_ };  // q
    ga.p[1] = { wsA + 1 * MH_, wsW + 1 * HH_, in[9],  wsP + 1 * MH_ };  // k
    ga.p[2] = { wsA + 2 * MH_, wsW + 2 * HH_, in[11], wsP + 2 * MH_ };  // v
    ga.p[3] = { wsA + 3 * MH_, wsW + 3 * HH_, in[13], wsP + 3 * MH_ };  // qp
    ga.p[4] = { wsA + 3 * MH_, wsW + 4 * HH_, in[15], wsP + 4 * MH_ };  // kp
    ga.p[5] = { wsA + 4 * MH_, wsW + 5 * HH_, in[17], wsP + 5 * MH_ };  // qf
    ga.p[6] = { wsA + 4 * MH_, wsW + 6 * HH_, in[19], wsP + 6 * MH_ };  // kf
    mfma_gemm<true><<<dim3(1792), 256, 0, stream>>>(ga, 1792);

    // 3) MFMA flash attention: content map -> out + MH_ (fp32), ctx -> wsC (bf16)
    attn_kernel<<<dim3(1024), 256, 0, stream>>>(wsP, in[3], out + MH_, wsC);

    // 4) output projection (A bf16, out fp32)
    GemmArgs gf;
    gf.p[0] = { wsC, wsW + 7 * HH_, in[21], out };
    for (int i = 1; i < 7; ++i) gf.p[i] = gf.p[0];
    mfma_gemm<false><<<dim3(256), 256, 0, stream>>>(gf, 256);
}